// Round 1
// 291.885 us; speedup vs baseline: 1.0273x; 1.0273x over previous
//
#include <hip/hip_runtime.h>
#include <math.h>

#define EPS_BN 1e-5f

typedef __attribute__((ext_vector_type(8))) short bf16x8;
typedef __attribute__((ext_vector_type(4))) float f32x4;
typedef __attribute__((ext_vector_type(2))) float f32x2;

// ---------------------------------------------------------------------------
// async global->LDS, 16B per lane
// ---------------------------------------------------------------------------
__device__ __forceinline__ void gld_lds16(const void* g, void* l) {
    __builtin_amdgcn_global_load_lds(
        (const __attribute__((address_space(1))) unsigned int*)g,
        (__attribute__((address_space(3))) unsigned int*)l, 16, 0, 0);
}

__device__ __forceinline__ unsigned short f2bf(float f) {  // RNE fp32->bf16
    unsigned u = __float_as_uint(f);
    return (unsigned short)((u + 0x7FFFu + ((u >> 16) & 1u)) >> 16);
}

// Bit-exact fp32 distance vs np reference: sources pre-doubled so
// rn(tx*2sx) = 2*rn(tx*sx) exactly; d = rn(rn(sumT - dot2) + sumS).
__device__ __forceinline__ float dist_exact(float4 T, float4 s) {
    float dot2 = __fadd_rn(__fadd_rn(__fmul_rn(T.x, s.x), __fmul_rn(T.y, s.y)),
                           __fmul_rn(T.z, s.z));
    return __fadd_rn(__fsub_rn(T.w, dot2), s.w);
}

// ---------------------------------------------------------------------------
// fp32 [M][K] -> bf16 tile-packed swizzled: granule rotation
// g=((k>>3)+(r>>1))&3 makes MFMA fragment ds_read_b128 2-lanes/bank (free).
// ---------------------------------------------------------------------------
__device__ __forceinline__ void conv_body(
    const float* __restrict__ src, unsigned short* __restrict__ dst,
    int blk, int tid, int K8log, int nslab)
{
    const int gid = blk * 256 + tid;
    const int m  = gid >> K8log;
    const int ko = gid & ((1 << K8log) - 1);
    const float4* s = (const float4*)src + ((size_t)m << (K8log + 1)) + ko * 2;
    float4 f0 = s[0];
    float4 f1 = s[1];
    const int mblk = m >> 7, r = m & 127;
    const int slab = ko >> 2, o = ko & 3;
    const int g = (o + (r >> 1)) & 3;
    unsigned short h[8] = {f2bf(f0.x), f2bf(f0.y), f2bf(f0.z), f2bf(f0.w),
                           f2bf(f1.x), f2bf(f1.y), f2bf(f1.z), f2bf(f1.w)};
    *(uint4*)(dst + ((size_t)(mblk * nslab + slab)) * 4096 + r * 32 + g * 8) =
        *(uint4*)h;
}

// ---------------------------------------------------------------------------
// One fused prep dispatch: bf16 pack A1/A2/W1/W2 + xyz packing.
//   sxyz1[i]   = (2x, 2y, 2z, |s|^2)  (AoS, for exact tail re-select)
//   sxyz1_soa  = per (batch,part,octet) blocks of 32 floats:
//                x[8], y[8], z[8], w[8]  (pair-contiguous for v_pk scan)
//   txyz2[i]   = (x, y, z, |t|^2)
// ---------------------------------------------------------------------------
__global__ __launch_bounds__(256) void prep_all(
    const float* __restrict__ p1, const float* __restrict__ p2,
    const float* __restrict__ w1, const float* __restrict__ w2,
    unsigned short* __restrict__ A1p, unsigned short* __restrict__ A2p,
    unsigned short* __restrict__ W1p, unsigned short* __restrict__ W2p,
    const float* __restrict__ xyz1, const float* __restrict__ xyz2,
    float4* __restrict__ sxyz1, float* __restrict__ sxyz1_soa,
    float4* __restrict__ txyz2)
{
    const int blk = blockIdx.x, tid = threadIdx.x;
    if (blk < 4096)        conv_body(p1, A1p, blk,         tid, 6, 16);
    else if (blk < 12288)  conv_body(p2, A2p, blk - 4096,  tid, 5, 8);
    else if (blk < 12352)  conv_body(w1, W1p, blk - 12288, tid, 6, 16);
    else if (blk < 12384)  conv_body(w2, W2p, blk - 12352, tid, 5, 8);
    else if (blk < 12448) {                       // xyz1 pack: 16384 sources
        int i = (blk - 12384) * 256 + tid;
        float x = xyz1[i * 3 + 0], y = xyz1[i * 3 + 1], z = xyz1[i * 3 + 2];
        float ss = __fadd_rn(__fadd_rn(__fmul_rn(x, x), __fmul_rn(y, y)),
                             __fmul_rn(z, z));
        float x2 = x + x, y2 = y + y, z2 = z + z;
        sxyz1[i] = make_float4(x2, y2, z2, ss);
        // SoA scatter for the packed-math scan
        const int b = i >> 12, s = i & 4095;
        const int p = s >> 9, o = (s >> 3) & 63, e = s & 7;
        float* soa = sxyz1_soa + (((size_t)(b * 8 + p)) * 64 + o) * 32;
        soa[e]      = x2;
        soa[8 + e]  = y2;
        soa[16 + e] = z2;
        soa[24 + e] = ss;
    } else {                                      // xyz2 pack: 65536 targets
        int i = (blk - 12448) * 256 + tid;
        float x = xyz2[i * 3 + 0], y = xyz2[i * 3 + 1], z = xyz2[i * 3 + 2];
        float st = __fadd_rn(__fadd_rn(__fmul_rn(x, x), __fmul_rn(y, y)),
                             __fmul_rn(z, z));
        txyz2[i] = make_float4(x, y, z, st);
    }
}

// ---------------------------------------------------------------------------
// KNN phase 1 v4: octet-min scan with packed fp32 (v_pk_mul/add) distances.
// Per octet of 8 sources: 8 exact distances via 4 f32x2 lanes (mul/add only,
// contraction off -> bit-identical op sequence to dist_exact) -> dmin;
// maintain stable top-3 (dmin, octet idx) via cmp+cndmask (strict < keeps
// earliest octet on ties). Containment: the 3 best octets by stable
// octet-min key contain all top-3 singles (any octet beating octet O's min
// contains a single whose stable key beats every single in O achieving the
// min). Post-scan: exact stable re-select over the 24 candidate singles
// (AoS gathers) with f64-packed keys == lax.top_k stable semantics.
// ---------------------------------------------------------------------------
__global__ __launch_bounds__(256) void knn_select(
    const float4* __restrict__ sxyz1,     // AoS (2x,2y,2z,|s|^2), tail gathers
    const float*  __restrict__ sxyz1_soa, // SoA octet blocks, scan stream
    const float4* __restrict__ txyz2,     // packed (x,y,z,|t|^2)
    double* __restrict__ cand)            // [65536][8 parts][3] keys
{
#pragma clang fp contract(off)
    const int tid   = threadIdx.x;
    const int blk   = blockIdx.x;        // 0..2047
    const int part  = blk & 7;
    const int chunk = (blk >> 3) & 63;
    const int b     = blk >> 9;

    const int g = b * 16384 + chunk * 256 + tid;
    const float4 T = txyz2[g];
    const float* __restrict__ P =
        sxyz1_soa + ((size_t)(b * 8 + part)) * 2048;   // 64 octets * 32 floats
    const float4* __restrict__ S = sxyz1 + b * 4096 + part * 512;

    const f32x2 Txx = {T.x, T.x};
    const f32x2 Tyy = {T.y, T.y};
    const f32x2 Tzz = {T.z, T.z};
    const f32x2 Tww = {T.w, T.w};

    float d0 = INFINITY, d1 = INFINITY, d2 = INFINITY;
    int   q0 = 0,        q1 = 0,        q2 = 0;

#pragma unroll 2
    for (int o = 0; o < 64; o++) {
        const float* blkp = P + o * 32;    // wave-uniform stream
        f32x2 da, db, dc, dd;
        {
            f32x2 sx = *(const f32x2*)(blkp + 0);
            f32x2 sy = *(const f32x2*)(blkp + 8);
            f32x2 sz = *(const f32x2*)(blkp + 16);
            f32x2 sw = *(const f32x2*)(blkp + 24);
            f32x2 dot2 = (Txx * sx + Tyy * sy) + Tzz * sz;
            da = (Tww - dot2) + sw;
        }
        {
            f32x2 sx = *(const f32x2*)(blkp + 2);
            f32x2 sy = *(const f32x2*)(blkp + 10);
            f32x2 sz = *(const f32x2*)(blkp + 18);
            f32x2 sw = *(const f32x2*)(blkp + 26);
            f32x2 dot2 = (Txx * sx + Tyy * sy) + Tzz * sz;
            db = (Tww - dot2) + sw;
        }
        {
            f32x2 sx = *(const f32x2*)(blkp + 4);
            f32x2 sy = *(const f32x2*)(blkp + 12);
            f32x2 sz = *(const f32x2*)(blkp + 20);
            f32x2 sw = *(const f32x2*)(blkp + 28);
            f32x2 dot2 = (Txx * sx + Tyy * sy) + Tzz * sz;
            dc = (Tww - dot2) + sw;
        }
        {
            f32x2 sx = *(const f32x2*)(blkp + 6);
            f32x2 sy = *(const f32x2*)(blkp + 14);
            f32x2 sz = *(const f32x2*)(blkp + 22);
            f32x2 sw = *(const f32x2*)(blkp + 30);
            f32x2 dot2 = (Txx * sx + Tyy * sy) + Tzz * sz;
            dd = (Tww - dot2) + sw;
        }
        float mab = fminf(fminf(da[0], da[1]), fminf(db[0], db[1]));
        float mcd = fminf(fminf(dc[0], dc[1]), fminf(dd[0], dd[1]));
        float dm  = fminf(mab, mcd);

        bool c2 = dm < d2, c1 = dm < d1, c0 = dm < d0;
        float t2 = c1 ? d1 : (c2 ? dm : d2);
        int   u2 = c1 ? q1 : (c2 ? o : q2);
        float t1 = c0 ? d0 : (c1 ? dm : d1);
        int   u1 = c0 ? q0 : (c1 ? o : q1);
        float t0 = c0 ? dm : d0;
        int   u0 = c0 ? o : q0;
        d2 = t2; q2 = u2; d1 = t1; q1 = u1; d0 = t0; q0 = u0;
    }

    // exact stable re-select over 24 candidate singles (AoS, L1/L2-hot)
    const double INIT = __hiloint2double(0x7F800000, 0);   // huge finite key
    double k0 = INIT, k1 = INIT, k2 = INIT;
#pragma unroll
    for (int c = 0; c < 3; c++) {
        const int qq = (c == 0) ? q0 : ((c == 1) ? q1 : q2);
#pragma unroll
        for (int e = 0; e < 8; e++) {
            float4 s = S[qq * 8 + e];          // divergent gather (cache-hot)
            float d = dist_exact(T, s);
            double k = __hiloint2double(__float_as_int(d),
                                        part * 512 + qq * 8 + e);
            if (k < k2) {
                if (k < k1) {
                    k2 = k1;
                    if (k < k0) { k1 = k0; k0 = k; }
                    else        { k1 = k; }
                } else { k2 = k; }
            }
        }
    }

    double* c = cand + (size_t)g * 24 + part * 3;
    c[0] = k0; c[1] = k1; c[2] = k2;
}

// ---------------------------------------------------------------------------
// KNN phase 2: merge 8x3 candidate keys -> final top-3 + fp32 weights.
// ---------------------------------------------------------------------------
__global__ __launch_bounds__(256) void knn_merge(
    const double* __restrict__ cand, float* __restrict__ w3,
    int* __restrict__ idx3)
{
    const int g = blockIdx.x * 256 + threadIdx.x;
    const double INIT = __hiloint2double(0x7F800000, 0);
    double k0 = INIT, k1 = INIT, k2 = INIT;
#pragma unroll
    for (int p = 0; p < 24; p++) {
        double k = cand[(size_t)g * 24 + p];
        if (k < k2) {
            if (k < k1) {
                k2 = k1;
                if (k < k0) { k1 = k0; k0 = k; }
                else        { k1 = k; }
            } else { k2 = k; }
        }
    }
    float d0 = __int_as_float(__double2hiint(k0));
    float d1 = __int_as_float(__double2hiint(k1));
    float d2 = __int_as_float(__double2hiint(k2));
    float w0 = 1.0f / __fadd_rn(d0, 1e-8f);
    float w1 = 1.0f / __fadd_rn(d1, 1e-8f);
    float w2 = 1.0f / __fadd_rn(d2, 1e-8f);
    float ws = __fadd_rn(__fadd_rn(w0, w1), w2);
    w3[(size_t)g * 3 + 0] = w0 / ws;
    w3[(size_t)g * 3 + 1] = w1 / ws;
    w3[(size_t)g * 3 + 2] = w2 / ws;
    idx3[(size_t)g * 3 + 0] = __double2loint(k0);
    idx3[(size_t)g * 3 + 1] = __double2loint(k1);
    idx3[(size_t)g * 3 + 2] = __double2loint(k2);
}

// ---------------------------------------------------------------------------
// bf16 MFMA GEMM + BN + ReLU (verified since R3). Used for feats1.
// ---------------------------------------------------------------------------
__global__ __launch_bounds__(256) void gemm_bf16_bn_relu(
    const unsigned short* __restrict__ Ap,
    const unsigned short* __restrict__ Bp,
    const float* __restrict__ bias,
    const float* __restrict__ gamma,
    const float* __restrict__ beta,
    const float* __restrict__ mean,
    const float* __restrict__ var,
    float* __restrict__ out, int M, int K)
{
    __shared__ __align__(16) unsigned short As[4096];
    __shared__ __align__(16) unsigned short Bs[4096];

    const int tid  = threadIdx.x;
    const int w    = tid >> 6;
    const int lane = tid & 63;
    const int q    = lane >> 4;
    const int rl   = lane & 15;
    const int wm   = w >> 1, wn = w & 1;
    const int bn   = blockIdx.x, bm = blockIdx.y;
    const int nslab = K >> 5;

    f32x4 acc[4][4];
#pragma unroll
    for (int i = 0; i < 4; i++)
#pragma unroll
        for (int j = 0; j < 4; j++) acc[i][j] = (f32x4){0.f, 0.f, 0.f, 0.f};

    const unsigned short* Ab = Ap + (size_t)bm * nslab * 4096;
    const unsigned short* Bb = Bp + (size_t)bn * nslab * 4096;
    const int c0 = 2 * w;
    const int l8 = lane * 8;

    int aidx[4], bidx[4];
#pragma unroll
    for (int i = 0; i < 4; i++) {
        int rr = wm * 64 + i * 16 + rl;
        aidx[i] = rr * 32 + ((q + (rr >> 1)) & 3) * 8;
        int nn = wn * 64 + i * 16 + rl;
        bidx[i] = nn * 32 + ((q + (nn >> 1)) & 3) * 8;
    }

    for (int s = 0; s < nslab; s++) {
        __syncthreads();
        const unsigned short* a = Ab + (size_t)s * 4096;
        const unsigned short* b = Bb + (size_t)s * 4096;
        gld_lds16(a + (c0 + 0) * 512 + l8, &As[(c0 + 0) * 512 + l8]);
        gld_lds16(a + (c0 + 1) * 512 + l8, &As[(c0 + 1) * 512 + l8]);
        gld_lds16(b + (c0 + 0) * 512 + l8, &Bs[(c0 + 0) * 512 + l8]);
        gld_lds16(b + (c0 + 1) * 512 + l8, &Bs[(c0 + 1) * 512 + l8]);
        __syncthreads();

        bf16x8 af[4], bf[4];
#pragma unroll
        for (int i = 0; i < 4; i++) af[i] = *(const bf16x8*)&As[aidx[i]];
#pragma unroll
        for (int j = 0; j < 4; j++) bf[j] = *(const bf16x8*)&Bs[bidx[j]];
#pragma unroll
        for (int i = 0; i < 4; i++)
#pragma unroll
            for (int j = 0; j < 4; j++)
                acc[i][j] = __builtin_amdgcn_mfma_f32_16x16x32_bf16(
                    af[i], bf[j], acc[i][j], 0, 0, 0);
    }

    const int gm0 = bm * 128 + wm * 64;
    const int gn0 = bn * 128 + wn * 64;
#pragma unroll
    for (int j = 0; j < 4; j++) {
        int n = gn0 + j * 16 + rl;
        float sc = gamma[n] / sqrtf(var[n] + EPS_BN);
        float sh = beta[n] + (bias[n] - mean[n]) * sc;
#pragma unroll
        for (int i = 0; i < 4; i++) {
            int m0 = gm0 + i * 16 + q * 4;
#pragma unroll
            for (int t = 0; t < 4; t++) {
                float v = fmaxf(acc[i][j][t] * sc + sh, 0.f);
                out[(size_t)(m0 + t) * 256 + n] = v;
            }
        }
    }
}

// ---------------------------------------------------------------------------
// GEMM2 + BN + ReLU + fused 3-NN interpolation add:
//   out[m][n] = relu(BN(A2@W2^T)) + sum_k w3[m][k] * feats1[b(m), idx3[m][k]][n]
// Same GEMM core; epilogue gathers feats1 rows (64B-coalesced per 16-lane
// group) and adds before the single store — kills the 128 MB out RMW.
// ---------------------------------------------------------------------------
__global__ __launch_bounds__(256) void gemm2_interp(
    const unsigned short* __restrict__ Ap,
    const unsigned short* __restrict__ Bp,
    const float* __restrict__ bias,
    const float* __restrict__ gamma,
    const float* __restrict__ beta,
    const float* __restrict__ mean,
    const float* __restrict__ var,
    const float* __restrict__ feats1,   // [4*4096][256]
    const float* __restrict__ w3,       // [65536][3]
    const int*   __restrict__ idx3,     // [65536][3] (within-batch indices)
    float* __restrict__ out)
{
    __shared__ __align__(16) unsigned short As[4096];
    __shared__ __align__(16) unsigned short Bs[4096];

    const int tid  = threadIdx.x;
    const int w    = tid >> 6;
    const int lane = tid & 63;
    const int q    = lane >> 4;
    const int rl   = lane & 15;
    const int wm   = w >> 1, wn = w & 1;
    const int bn   = blockIdx.x, bm = blockIdx.y;
    const int nslab = 8;                 // K = 256

    f32x4 acc[4][4];
#pragma unroll
    for (int i = 0; i < 4; i++)
#pragma unroll
        for (int j = 0; j < 4; j++) acc[i][j] = (f32x4){0.f, 0.f, 0.f, 0.f};

    const unsigned short* Ab = Ap + (size_t)bm * nslab * 4096;
    const unsigned short* Bb = Bp + (size_t)bn * nslab * 4096;
    const int c0 = 2 * w;
    const int l8 = lane * 8;

    int aidx[4], bidx[4];
#pragma unroll
    for (int i = 0; i < 4; i++) {
        int rr = wm * 64 + i * 16 + rl;
        aidx[i] = rr * 32 + ((q + (rr >> 1)) & 3) * 8;
        int nn = wn * 64 + i * 16 + rl;
        bidx[i] = nn * 32 + ((q + (nn >> 1)) & 3) * 8;
    }

    for (int s = 0; s < nslab; s++) {
        __syncthreads();
        const unsigned short* a = Ab + (size_t)s * 4096;
        const unsigned short* b = Bb + (size_t)s * 4096;
        gld_lds16(a + (c0 + 0) * 512 + l8, &As[(c0 + 0) * 512 + l8]);
        gld_lds16(a + (c0 + 1) * 512 + l8, &As[(c0 + 1) * 512 + l8]);
        gld_lds16(b + (c0 + 0) * 512 + l8, &Bs[(c0 + 0) * 512 + l8]);
        gld_lds16(b + (c0 + 1) * 512 + l8, &Bs[(c0 + 1) * 512 + l8]);
        __syncthreads();

        bf16x8 af[4], bf[4];
#pragma unroll
        for (int i = 0; i < 4; i++) af[i] = *(const bf16x8*)&As[aidx[i]];
#pragma unroll
        for (int j = 0; j < 4; j++) bf[j] = *(const bf16x8*)&Bs[bidx[j]];
#pragma unroll
        for (int i = 0; i < 4; i++)
#pragma unroll
            for (int j = 0; j < 4; j++)
                acc[i][j] = __builtin_amdgcn_mfma_f32_16x16x32_bf16(
                    af[i], bf[j], acc[i][j], 0, 0, 0);
    }

    const int gm0 = bm * 128 + wm * 64;
    const int gn0 = bn * 128 + wn * 64;
    float scj[4], shj[4];
    int nj[4];
#pragma unroll
    for (int j = 0; j < 4; j++) {
        int n = gn0 + j * 16 + rl;
        nj[j] = n;
        float sc = gamma[n] / sqrtf(var[n] + EPS_BN);
        scj[j] = sc;
        shj[j] = beta[n] + (bias[n] - mean[n]) * sc;
    }

#pragma unroll
    for (int i = 0; i < 4; i++) {
#pragma unroll
        for (int t = 0; t < 4; t++) {
            const int m = gm0 + i * 16 + q * 4 + t;      // global target row
            const int bb = m >> 14;                      // batch
            const int j0 = idx3[(size_t)m * 3 + 0];
            const int j1 = idx3[(size_t)m * 3 + 1];
            const int j2 = idx3[(size_t)m * 3 + 2];
            const float u0 = w3[(size_t)m * 3 + 0];
            const float u1 = w3[(size_t)m * 3 + 1];
            const float u2 = w3[(size_t)m * 3 + 2];
            const float* f0 = feats1 + ((size_t)(bb * 4096 + j0)) * 256;
            const float* f1 = feats1 + ((size_t)(bb * 4096 + j1)) * 256;
            const float* f2 = feats1 + ((size_t)(bb * 4096 + j2)) * 256;
#pragma unroll
            for (int j = 0; j < 4; j++) {
                const int n = nj[j];
                float v = fmaxf(acc[i][j][t] * scj[j] + shj[j], 0.f);
                v += u0 * f0[n] + u1 * f1[n] + u2 * f2[n];
                out[(size_t)m * 256 + n] = v;
            }
        }
    }
}

extern "C" void kernel_launch(void* const* d_in, const int* in_sizes, int n_in,
                              void* d_out, int out_size, void* d_ws, size_t ws_size,
                              hipStream_t stream) {
    const float* xyz1    = (const float*)d_in[0];
    const float* points1 = (const float*)d_in[1];
    const float* xyz2    = (const float*)d_in[2];
    const float* points2 = (const float*)d_in[3];
    const float* W1  = (const float*)d_in[4];
    const float* b1  = (const float*)d_in[5];
    const float* g1  = (const float*)d_in[6];
    const float* be1 = (const float*)d_in[7];
    const float* m1  = (const float*)d_in[8];
    const float* v1  = (const float*)d_in[9];
    const float* W2  = (const float*)d_in[10];
    const float* b2  = (const float*)d_in[11];
    const float* g2  = (const float*)d_in[12];
    const float* be2 = (const float*)d_in[13];
    const float* m2  = (const float*)d_in[14];
    const float* v2  = (const float*)d_in[15];

    const size_t MB = 1u << 20;
    char* ws = (char*)d_ws;
    // cand lives in [0,16)MB, dead before gemm1 writes feats1 there.
    float*          feats1 = (float*)(ws);                       // 16 MB
    double*         cand   = (double*)(ws);                      // 12.6 MB
    unsigned short* A1p    = (unsigned short*)(ws + 16 * MB);    // 16 MB
    unsigned short* A2p    = (unsigned short*)(ws + 32 * MB);    // 32 MB
    unsigned short* W1p    = (unsigned short*)(ws + 64 * MB);    // 0.5 MB
    unsigned short* W2p    = (unsigned short*)(ws + 64 * MB + 512 * 1024);
    float4*         sxyz1  = (float4*)(ws + 65 * MB);            // 256 KB
    float*          sxyz1s = (float*)(ws + 65 * MB + 256 * 1024); // 256 KB SoA
    float4*         txyz2  = (float4*)(ws + 66 * MB);            // 1 MB
    float*          w3     = (float*)(ws + 67 * MB);             // 0.75 MB
    int*            idx3   = (int*)(ws + 68 * MB);               // 0.75 MB
    float* outp = (float*)d_out;

    dim3 blk(256);
    // 1) all packing/conversion in one dispatch
    prep_all<<<12704, blk, 0, stream>>>(points1, points2, W1, W2,
                                        A1p, A2p, W1p, W2p,
                                        xyz1, xyz2, sxyz1, sxyz1s, txyz2);
    // 2-3) neighbor selection (independent of GEMMs)
    knn_select<<<2048, blk, 0, stream>>>(sxyz1, sxyz1s, txyz2, cand);
    knn_merge<<<256, blk, 0, stream>>>(cand, w3, idx3);
    // 4) feats1 = relu(BN(points1 @ W1^T))   (clobbers cand — cand is dead)
    gemm_bf16_bn_relu<<<dim3(2, 128), blk, 0, stream>>>(A1p, W1p, b1, g1, be1, m1, v1,
                                                        feats1, 16384, 512);
    // 5) out = relu(BN(points2 @ W2^T)) + interp3(xyz2 <- xyz1, feats1)
    gemm2_interp<<<dim3(2, 512), blk, 0, stream>>>(A2p, W2p, b2, g2, be2, m2, v2,
                                                   feats1, w3, idx3, outp);
}